// Round 1
// baseline (2952.483 us; speedup 1.0000x reference)
//
#include <hip/hip_runtime.h>

namespace {

constexpr int WSZ  = 7;
constexpr int SSZ  = 3;
constexpr int NHEAD = 4;
constexpr int HDIM = 32;
constexpr int CDIM = 128;
constexpr int NTOK = 49;      // WSZ*WSZ
constexpr int IMG  = 56;      // H = W
constexpr int NBLK = 4096;    // B(64) * windows(8*8)
constexpr float QSCALE = 0.17677669529663687f;  // 32^-0.5

__global__ __launch_bounds__(256) void swin_fused(
    const float* __restrict__ xin,    // [64][3136][128]
    const float* __restrict__ rpb,    // [169][4]
    const float* __restrict__ qkvw,   // [384][128]
    const float* __restrict__ qkvb,   // [384]
    const float* __restrict__ projw,  // [128][128]
    const float* __restrict__ projb,  // [128]
    float* __restrict__ outp)         // [64][3136][128]
{
  __shared__ float xs[NTOK][CDIM];        // 25,088 B  input tile (fp32)
  __shared__ float ot[NTOK][CDIM];        // 25,088 B  per-window attention output
  __shared__ float wT[CDIM][HDIM];        // 16,384 B  staged weight slice, TRANSPOSED
  __shared__ float qh[NTOK][HDIM];        //  6,272 B
  __shared__ float khT[HDIM][NTOK];       //  6,272 B  K stored transposed
  __shared__ float vh[NTOK][HDIM];        //  6,272 B
  __shared__ float att[NTOK][NTOK + 1];   //  9,800 B
  __shared__ int   codes[NTOK];
  __shared__ int   gpos[NTOK];            // original-image pixel index per token

  const int tid = threadIdx.x;
  const int wb  = blockIdx.x;
  const int bb  = wb >> 6;          // batch
  const int wy  = (wb >> 3) & 7;    // window row
  const int wx  = wb & 7;           // window col

  // token geometry: roll(-SS) => token (i,j) of window (wy,wx) maps to
  // original pixel ((wy*7+i+3)%56, (wx*7+j+3)%56); same map for output scatter.
  // mask region codes use UNROLLED partition coords (wy*7+i, wx*7+j).
  if (tid < NTOK) {
    int ti = tid / WSZ, tj = tid % WSZ;
    int mh = wy * WSZ + ti, mw = wx * WSZ + tj;
    int gh = (mh + SSZ) % IMG, gw = (mw + SSZ) % IMG;
    gpos[tid] = gh * IMG + gw;
    int rh = (mh < IMG - WSZ) ? 0 : ((mh < IMG - SSZ) ? 1 : 2);
    int rw = (mw < IMG - WSZ) ? 0 : ((mw < IMG - SSZ) ? 1 : 2);
    codes[tid] = rh * 3 + rw;
  }
  __syncthreads();

  // ---- Phase 0: gather input tile (coalesced float4 per pixel row) ----
  const float* xb = xin + (size_t)bb * (IMG * IMG) * CDIM;
  for (int k = tid; k < NTOK * (CDIM / 4); k += 256) {
    int n = k >> 5, c4 = k & 31;
    float4 v = *reinterpret_cast<const float4*>(xb + (size_t)gpos[n] * CDIM + c4 * 4);
    *reinterpret_cast<float4*>(&xs[n][c4 * 4]) = v;
  }
  __syncthreads();

  // ---- Per-head attention ----
  for (int h = 0; h < NHEAD; ++h) {
    // QKV for this head: sections s = 0(q) 1(k) 2(v), 32 output cols each.
    for (int s = 0; s < 3; ++s) {
      const int row0 = s * CDIM + h * HDIM;
      // stage wT[c][d] = qkvw[row0+d][c]  (LDS writes conflict-free: lanes vary d)
      for (int k = tid; k < CDIM * HDIM; k += 256) {
        int c = k >> 5, d = k & 31;
        wT[c][d] = qkvw[(size_t)(row0 + d) * CDIM + c];
      }
      __syncthreads();
      // out[n][d] = dot(xs[n], w_row[d]) + b; xs read broadcast, wT coalesced.
      for (int o = tid; o < NTOK * HDIM; o += 256) {
        int n = o >> 5, d = o & 31;
        const float* xr = xs[n];
        float a0 = 0.f, a1 = 0.f, a2 = 0.f, a3 = 0.f;
        #pragma unroll 8
        for (int c = 0; c < CDIM; c += 4) {
          a0 += xr[c + 0] * wT[c + 0][d];
          a1 += xr[c + 1] * wT[c + 1][d];
          a2 += xr[c + 2] * wT[c + 2][d];
          a3 += xr[c + 3] * wT[c + 3][d];
        }
        float acc = (a0 + a1) + (a2 + a3) + qkvb[row0 + d];
        if (s == 0)      qh[n][d]  = acc * QSCALE;
        else if (s == 1) khT[d][n] = acc;   // transposed store (conflict-free)
        else             vh[n][d]  = acc;
      }
      __syncthreads();
    }

    // QK^T + rel-pos bias + shift mask
    for (int o = tid; o < NTOK * NTOK; o += 256) {
      int a = o / NTOK, b = o % NTOK;
      const float* qr = qh[a];
      float acc = 0.f;
      #pragma unroll 8
      for (int d = 0; d < HDIM; ++d) acc += qr[d] * khT[d][b];
      int ia = a / WSZ, ja = a % WSZ, ib = b / WSZ, jb = b % WSZ;
      int ridx = 13 * (ia - ib + 6) + (ja - jb + 6);   // (2*WS-1)=13
      float bias = rpb[ridx * NHEAD + h];
      float msk = (codes[a] == codes[b]) ? 0.f : -100.f;
      att[a][b] = acc + bias + msk;
    }
    __syncthreads();

    // softmax per row (one thread per row; small fraction of total work)
    if (tid < NTOK) {
      float m = -1e30f;
      for (int b2 = 0; b2 < NTOK; ++b2) m = fmaxf(m, att[tid][b2]);
      float ssum = 0.f;
      for (int b2 = 0; b2 < NTOK; ++b2) {
        float e = __expf(att[tid][b2] - m);
        att[tid][b2] = e;
        ssum += e;
      }
      float inv = 1.0f / ssum;
      for (int b2 = 0; b2 < NTOK; ++b2) att[tid][b2] *= inv;
    }
    __syncthreads();

    // PV: ot[a][h*32+d] = sum_b att[a][b] * vh[b][d]
    for (int o = tid; o < NTOK * HDIM; o += 256) {
      int a = o >> 5, d = o & 31;
      float acc = 0.f;
      #pragma unroll 7
      for (int b2 = 0; b2 < NTOK; ++b2) acc += att[a][b2] * vh[b2][d];
      ot[a][h * HDIM + d] = acc;
    }
    __syncthreads();
  }

  // ---- Output projection + window-reverse scatter ----
  for (int r0 = 0; r0 < CDIM; r0 += HDIM) {
    for (int k = tid; k < CDIM * HDIM; k += 256) {
      int c = k >> 5, d = k & 31;
      wT[c][d] = projw[(size_t)(r0 + d) * CDIM + c];
    }
    __syncthreads();
    for (int o = tid; o < NTOK * HDIM; o += 256) {
      int n = o >> 5, d = o & 31;
      const float* orow = ot[n];
      float a0 = 0.f, a1 = 0.f, a2 = 0.f, a3 = 0.f;
      #pragma unroll 8
      for (int c = 0; c < CDIM; c += 4) {
        a0 += orow[c + 0] * wT[c + 0][d];
        a1 += orow[c + 1] * wT[c + 1][d];
        a2 += orow[c + 2] * wT[c + 2][d];
        a3 += orow[c + 3] * wT[c + 3][d];
      }
      float acc = (a0 + a1) + (a2 + a3) + projb[r0 + d];
      outp[(size_t)bb * (IMG * IMG * CDIM) + (size_t)gpos[n] * CDIM + (r0 + d)] = acc;
    }
    __syncthreads();
  }
}

}  // namespace

extern "C" void kernel_launch(void* const* d_in, const int* in_sizes, int n_in,
                              void* d_out, int out_size, void* d_ws, size_t ws_size,
                              hipStream_t stream) {
  const float* x     = (const float*)d_in[0];
  const float* rpb   = (const float*)d_in[1];
  const float* qkvw  = (const float*)d_in[2];
  const float* qkvb  = (const float*)d_in[3];
  const float* projw = (const float*)d_in[4];
  const float* projb = (const float*)d_in[5];
  swin_fused<<<NBLK, 256, 0, stream>>>(x, rpb, qkvw, qkvb, projw, projb, (float*)d_out);
}

// Round 2
// 276.167 us; speedup vs baseline: 10.6909x; 10.6909x over previous
//
#include <hip/hip_runtime.h>

typedef short s16x8 __attribute__((ext_vector_type(8)));
typedef float f32x4 __attribute__((ext_vector_type(4)));
typedef unsigned short u16;

namespace {

constexpr int NHEAD = 4;
constexpr int CDIM  = 128;
constexpr int NTOK  = 49;
constexpr int IMG   = 56;
constexpr int NBLK  = 4096;
constexpr float QSCALE = 0.17677669529663687f;  // 32^-0.5

__device__ inline u16 f2bf(float x) {
  unsigned u = __float_as_uint(x);
  u += 0x7fffu + ((u >> 16) & 1u);
  return (u16)(u >> 16);
}

// ---- prep: convert weights to bf16 once per launch (L2-resident, 128 KB) ----
__global__ void cvt_weights(const float* __restrict__ qkvw,
                            const float* __restrict__ projw,
                            u16* __restrict__ wq, u16* __restrict__ wp) {
  int i = blockIdx.x * 256 + threadIdx.x;
  if (i < 384 * 128) wq[i] = f2bf(qkvw[i]);
  if (i < 128 * 128) wp[i] = f2bf(projw[i]);
}

// swizzle: element (r,c) of a row-major [R][128] bf16 tile lives at
//   r*128 + (c&7) + 8*((c>>3) ^ (r&7));   64-col tiles analogous.
// Fragment loads (8 contiguous c, c0%8==0) are then single 16B-aligned
// ds_read_b128 with slot%8 = (G^(r&7))%8 -> 2-way max (free, m136).

__global__ __launch_bounds__(256, 2) void swin_mfma(
    const float* __restrict__ xin,    // [64][3136][128] f32
    const float* __restrict__ rpb,    // [169][4] f32
    const float* __restrict__ qkvb,   // [384] f32
    const float* __restrict__ projb,  // [128] f32
    const u16*  __restrict__ wq,      // [384][128] bf16
    const u16*  __restrict__ wp,      // [128][128] bf16
    float* __restrict__ outp)         // [64][3136][128] f32
{
  __shared__ u16 xsot[64 * 128];   // X tile, later reused as attn-output tile
  __shared__ u16 Qs[64 * 128];
  __shared__ u16 Ks[64 * 128];
  __shared__ u16 VTs[128 * 64];    // V transposed: [dim][token]
  __shared__ u16 atts[64 * 64];
  __shared__ float rpbs[169 * NHEAD];
  __shared__ int gposs[64], codess[64], tokIs[64], tokJs[64];

  const int tid  = threadIdx.x;
  const int wb   = blockIdx.x;
  const int bb   = wb >> 6, wy = (wb >> 3) & 7, wx = wb & 7;
  const int wave = tid >> 6, lane = tid & 63;
  const int g    = lane >> 4, lj = lane & 15;

  if (tid < 64) {
    int t  = min(tid, 48);
    int ti = (t * 9363) >> 16;          // t/7 for t<64
    int tj = t - ti * 7;
    tokIs[tid] = ti; tokJs[tid] = tj;
    int mh = wy * 7 + ti, mw = wx * 7 + tj;
    gposs[tid] = ((mh + 3) % IMG) * IMG + (mw + 3) % IMG;
    int rh = (mh < 49) ? 0 : ((mh < 53) ? 1 : 2);
    int rw = (mw < 49) ? 0 : ((mw < 53) ? 1 : 2);
    codess[tid] = rh * 3 + rw;
  }
  for (int i = tid; i < 169 * NHEAD; i += 256) rpbs[i] = rpb[i];
  __syncthreads();

  // ---- gather X -> bf16 swizzled LDS (pad rows 49-63 with zeros) ----
  const float* xb = xin + (size_t)bb * (IMG * IMG * CDIM);
  for (int k2 = tid; k2 < 64 * 16; k2 += 256) {
    int r = k2 >> 4, G = k2 & 15;
    s16x8 v8 = {0, 0, 0, 0, 0, 0, 0, 0};
    if (r < NTOK) {
      const float* src = xb + (size_t)gposs[r] * CDIM + G * 8;
      float4 a = *reinterpret_cast<const float4*>(src);
      float4 b = *reinterpret_cast<const float4*>(src + 4);
      v8[0] = (short)f2bf(a.x); v8[1] = (short)f2bf(a.y);
      v8[2] = (short)f2bf(a.z); v8[3] = (short)f2bf(a.w);
      v8[4] = (short)f2bf(b.x); v8[5] = (short)f2bf(b.y);
      v8[6] = (short)f2bf(b.z); v8[7] = (short)f2bf(b.w);
    }
    *reinterpret_cast<s16x8*>(&xsot[r * 128 + 8 * (G ^ (r & 7))]) = v8;
  }
  __syncthreads();

  // ---- QKV GEMM: [64x128] @ [128x384]; wave w owns 6 col-tiles ----
  f32x4 acc[6][4];
  #pragma unroll
  for (int jj = 0; jj < 6; ++jj)
    #pragma unroll
    for (int mt = 0; mt < 4; ++mt) acc[jj][mt] = (f32x4){0.f, 0.f, 0.f, 0.f};

  #pragma unroll
  for (int ks = 0; ks < 4; ++ks) {
    s16x8 afr[4];
    #pragma unroll
    for (int mt = 0; mt < 4; ++mt)
      afr[mt] = *reinterpret_cast<const s16x8*>(
          &xsot[(16 * mt + lj) * 128 + 8 * ((4 * ks + g) ^ (lj & 7))]);
    #pragma unroll
    for (int jj = 0; jj < 6; ++jj) {
      int col0 = 96 * wave + 16 * jj;
      s16x8 bfr = *reinterpret_cast<const s16x8*>(
          &wq[(size_t)(col0 + lj) * 128 + ks * 32 + 8 * g]);
      #pragma unroll
      for (int mt = 0; mt < 4; ++mt)
        acc[jj][mt] = __builtin_amdgcn_mfma_f32_16x16x32_bf16(
            afr[mt], bfr, acc[jj][mt], 0, 0, 0);
    }
  }
  // epilogue: +bias, scale Q, scatter bf16 into Qs/Ks/VTs (swizzled)
  #pragma unroll
  for (int jj = 0; jj < 6; ++jj) {
    int col0 = 96 * wave + 16 * jj;
    int col  = col0 + lj;
    float bias = qkvb[col];
    int sec = col0 >> 7;      // 0=Q 1=K 2=V (tiles never straddle sections)
    int c   = col & 127;
    #pragma unroll
    for (int mt = 0; mt < 4; ++mt) {
      #pragma unroll
      for (int r2 = 0; r2 < 4; ++r2) {
        int tok = 16 * mt + 4 * g + r2;
        float val = acc[jj][mt][r2] + bias;
        if (sec == 0)
          Qs[tok * 128 + (c & 7) + 8 * ((c >> 3) ^ (tok & 7))] = f2bf(val * QSCALE);
        else if (sec == 1)
          Ks[tok * 128 + (c & 7) + 8 * ((c >> 3) ^ (tok & 7))] = f2bf(val);
        else
          VTs[c * 64 + (tok & 7) + 8 * ((tok >> 3) ^ (c & 7))] = f2bf(val);
      }
    }
  }
  __syncthreads();

  // ---- per-head attention; wave w owns row-strip [16w, 16w+16) ----
  for (int h = 0; h < NHEAD; ++h) {
    asm volatile("" ::: "memory");
    f32x4 qk[4];
    #pragma unroll
    for (int jt = 0; jt < 4; ++jt) qk[jt] = (f32x4){0.f, 0.f, 0.f, 0.f};
    s16x8 qa = *reinterpret_cast<const s16x8*>(
        &Qs[(16 * wave + lj) * 128 + 8 * ((4 * h + g) ^ (lj & 7))]);
    #pragma unroll
    for (int jt = 0; jt < 4; ++jt) {
      s16x8 kb = *reinterpret_cast<const s16x8*>(
          &Ks[(16 * jt + lj) * 128 + 8 * ((4 * h + g) ^ (lj & 7))]);
      qk[jt] = __builtin_amdgcn_mfma_f32_16x16x32_bf16(qa, kb, qk[jt], 0, 0, 0);
    }
    // bias + mask; rows n = 16w+4g+r2, cols m = 16jt+lj
    float mx[4] = {-3e38f, -3e38f, -3e38f, -3e38f};
    const int nbase = 16 * wave + 4 * g;
    #pragma unroll
    for (int jt = 0; jt < 4; ++jt) {
      int m  = 16 * jt + lj;
      int ma = min(m, 48);
      #pragma unroll
      for (int r2 = 0; r2 < 4; ++r2) {
        int na = min(nbase + r2, 48);
        int ridx = 13 * (tokIs[na] - tokIs[ma] + 6) + (tokJs[na] - tokJs[ma] + 6);
        float s = qk[jt][r2] + rpbs[ridx * NHEAD + h];
        if (m >= NTOK) s = -3e38f;
        else if (codess[na] != codess[ma]) s -= 100.f;
        qk[jt][r2] = s;
        mx[r2] = fmaxf(mx[r2], s);
      }
    }
    // wave-parallel softmax: reduce across the 16 lanes holding each row
    #pragma unroll
    for (int r2 = 0; r2 < 4; ++r2) {
      #pragma unroll
      for (int off = 8; off >= 1; off >>= 1)
        mx[r2] = fmaxf(mx[r2], __shfl_xor(mx[r2], off, 64));
    }
    float sm[4] = {0.f, 0.f, 0.f, 0.f};
    #pragma unroll
    for (int jt = 0; jt < 4; ++jt)
      #pragma unroll
      for (int r2 = 0; r2 < 4; ++r2) {
        float e = __expf(qk[jt][r2] - mx[r2]);
        qk[jt][r2] = e;
        sm[r2] += e;
      }
    #pragma unroll
    for (int r2 = 0; r2 < 4; ++r2) {
      #pragma unroll
      for (int off = 8; off >= 1; off >>= 1)
        sm[r2] += __shfl_xor(sm[r2], off, 64);
      sm[r2] = 1.f / sm[r2];
    }
    #pragma unroll
    for (int jt = 0; jt < 4; ++jt)
      #pragma unroll
      for (int r2 = 0; r2 < 4; ++r2) {
        int nn = nbase + r2, m = 16 * jt + lj;
        atts[nn * 64 + (m & 7) + 8 * ((m >> 3) ^ (nn & 7))] = f2bf(qk[jt][r2] * sm[r2]);
      }
    asm volatile("" ::: "memory");

    // PV: [16x64] @ [64x32] per wave
    f32x4 pv[2] = {(f32x4){0.f, 0.f, 0.f, 0.f}, (f32x4){0.f, 0.f, 0.f, 0.f}};
    #pragma unroll
    for (int ks2 = 0; ks2 < 2; ++ks2) {
      s16x8 pa = *reinterpret_cast<const s16x8*>(
          &atts[(16 * wave + lj) * 64 + 8 * ((4 * ks2 + g) ^ (lj & 7))]);
      #pragma unroll
      for (int jt = 0; jt < 2; ++jt) {
        int d = 32 * h + 16 * jt + lj;
        s16x8 vb = *reinterpret_cast<const s16x8*>(
            &VTs[d * 64 + 8 * ((4 * ks2 + g) ^ (d & 7))]);
        pv[jt] = __builtin_amdgcn_mfma_f32_16x16x32_bf16(pa, vb, pv[jt], 0, 0, 0);
      }
    }
    #pragma unroll
    for (int jt = 0; jt < 2; ++jt)
      #pragma unroll
      for (int r2 = 0; r2 < 4; ++r2) {
        int tok = 16 * wave + 4 * g + r2;
        int c   = 32 * h + 16 * jt + lj;
        xsot[tok * 128 + (c & 7) + 8 * ((c >> 3) ^ (tok & 7))] = f2bf(pv[jt][r2]);
      }
  }
  asm volatile("" ::: "memory");

  // ---- proj: [64x128] @ [128x128], + scatter to global ----
  f32x4 pr[8];
  #pragma unroll
  for (int jt = 0; jt < 8; ++jt) pr[jt] = (f32x4){0.f, 0.f, 0.f, 0.f};
  #pragma unroll
  for (int ks = 0; ks < 4; ++ks) {
    s16x8 pa = *reinterpret_cast<const s16x8*>(
        &xsot[(16 * wave + lj) * 128 + 8 * ((4 * ks + g) ^ (lj & 7))]);
    #pragma unroll
    for (int jt = 0; jt < 8; ++jt) {
      s16x8 pb = *reinterpret_cast<const s16x8*>(
          &wp[(size_t)(16 * jt + lj) * 128 + ks * 32 + 8 * g]);
      pr[jt] = __builtin_amdgcn_mfma_f32_16x16x32_bf16(pa, pb, pr[jt], 0, 0, 0);
    }
  }
  float* ob = outp + (size_t)bb * (IMG * IMG * CDIM);
  #pragma unroll
  for (int jt = 0; jt < 8; ++jt) {
    int col = 16 * jt + lj;
    float bias = projb[col];
    #pragma unroll
    for (int r2 = 0; r2 < 4; ++r2) {
      int tok = 16 * wave + 4 * g + r2;
      if (tok < NTOK)
        ob[(size_t)gposs[tok] * CDIM + col] = pr[jt][r2] + bias;
    }
  }
}

}  // namespace

extern "C" void kernel_launch(void* const* d_in, const int* in_sizes, int n_in,
                              void* d_out, int out_size, void* d_ws, size_t ws_size,
                              hipStream_t stream) {
  const float* x     = (const float*)d_in[0];
  const float* rpb   = (const float*)d_in[1];
  const float* qkvw  = (const float*)d_in[2];
  const float* qkvb  = (const float*)d_in[3];
  const float* projw = (const float*)d_in[4];
  const float* projb = (const float*)d_in[5];
  u16* wq = (u16*)d_ws;               // 384*128 bf16
  u16* wp = wq + 384 * 128;           // 128*128 bf16

  cvt_weights<<<192, 256, 0, stream>>>(qkvw, projw, wq, wp);
  swin_mfma<<<NBLK, 256, 0, stream>>>(x, rpb, qkvb, projb, wq, wp, (float*)d_out);
}